// Round 7
// baseline (263.878 us; speedup 1.0000x reference)
//
#include <hip/hip_runtime.h>

#define B_  8
#define C_  256
#define O_  256
#define H_  56
#define W_  56
#define HW_ 3136
#define KK_ 9
#define CK_ 2304   // C_*KK_
#define NKC 72     // K-chunks of 32

typedef __bf16    bf16x8 __attribute__((ext_vector_type(8)));
typedef float     f32x4  __attribute__((ext_vector_type(4)));

// async 16B/lane global->LDS: lds base wave-uniform; HW adds lane*16.
__device__ __forceinline__ void async16(const void* gsrc_lane, void* lds_uniform) {
    __builtin_amdgcn_global_load_lds(
        (const __attribute__((address_space(1))) unsigned int*)gsrc_lane,
        (__attribute__((address_space(3))) unsigned int*)lds_uniform, 16, 0, 0);
}

// XOR chunk swizzle: logical 16B-chunk q of row r stored at q ^ swz4(r).
__device__ __forceinline__ int swz4(int r) { return (r & 3) ^ ((r >> 2) & 3); }

__device__ __forceinline__ float blo(unsigned u) {
    return __builtin_bit_cast(float, u << 16);
}
__device__ __forceinline__ float bhi(unsigned u) {
    return __builtin_bit_cast(float, u & 0xffff0000u);
}
__device__ __forceinline__ unsigned pkbf(float lo, float hi) {
    unsigned short a = __builtin_bit_cast(unsigned short, (__bf16)lo);
    unsigned short b = __builtin_bit_cast(unsigned short, (__bf16)hi);
    return (unsigned)a | ((unsigned)b << 16);
}

// ---------------------------------------------------------------------------
// Kernel 1: wA[kc][m=256][32] bf16, tap-major K (g=kc*32+kl -> tap=g>>8,
// c=g&255), XOR chunk swizzle baked into the global image. 1.18 MB.
// ---------------------------------------------------------------------------
__global__ __launch_bounds__(256) void k_buildA(const float* __restrict__ w,
                                                unsigned short* __restrict__ wA) {
    int d  = blockIdx.x * 256 + threadIdx.x;   // exact 2304*256
    int kc = d >> 13;
    int rd = d & 8191;
    int m  = rd >> 5;
    int pos = rd & 31;
    int q  = (pos >> 3) ^ swz4(m);
    int kl = q * 8 + (pos & 7);
    int gk = kc * 32 + kl;
    int tap = gk >> 8, c = gk & 255;
    __bf16 v = (__bf16)w[m * CK_ + c * KK_ + tap];
    wA[d] = __builtin_bit_cast(unsigned short, v);
}

// ---------------------------------------------------------------------------
// Kernel 2: x NCHW f32 -> xT NHWC bf16 (12.85 MB). 64hw x 64c LDS tiles.
// ---------------------------------------------------------------------------
__global__ __launch_bounds__(256) void k_transx(const float* __restrict__ x,
                                                unsigned short* __restrict__ xT) {
    __shared__ float s[64][65];
    int bt   = blockIdx.x;            // 8 * 49 * 4
    int c64  = bt & 3;
    int hw64 = (bt >> 2) % 49;
    int b    = bt / 196;
    int tx = threadIdx.x & 63;
    int ty = threadIdx.x >> 6;
#pragma unroll
    for (int i = 0; i < 16; ++i)
        s[i * 4 + ty][tx] =
            x[((size_t)(b * 256 + c64 * 64 + i * 4 + ty)) * HW_ + hw64 * 64 + tx];
    __syncthreads();
#pragma unroll
    for (int i = 0; i < 16; ++i) {
        float v = s[tx][i * 4 + ty];
        xT[((size_t)b * HW_ + hw64 * 64 + i * 4 + ty) * 256 + c64 * 64 + tx] =
            __builtin_bit_cast(unsigned short, (__bf16)v);
    }
}

// ---------------------------------------------------------------------------
// Kernel 3a: offset conv partials, C split 4x64. (passed R6)
// ---------------------------------------------------------------------------
__global__ __launch_bounds__(512) void k_offc1(const float* __restrict__ x,
                                               const float* __restrict__ w_off,
                                               float* __restrict__ part) {
    __shared__ float partial[8][64][18];
    int t  = threadIdx.x;
    int p  = t & 63;
    int cg = __builtin_amdgcn_readfirstlane(t >> 6);
    int blk  = blockIdx.x;                    // 1568 = 392 units * 4 slices
    int sl   = blk & 3;
    int un   = blk >> 2;
    int b    = un / 49;
    int pos0 = (un % 49) * 64;
    int pos  = pos0 + p;
    int h = pos / W_;
    int w = pos % W_;
    const float* xb = x + (size_t)b * C_ * HW_;

    float acc[18];
#pragma unroll
    for (int i = 0; i < 18; ++i) acc[i] = 0.f;

    for (int cc = 0; cc < 8; ++cc) {
        int c = sl * 64 + cg * 8 + cc;
        const float* xp = xb + c * HW_;
        float v[9];
#pragma unroll
        for (int dh = -1; dh <= 1; ++dh)
#pragma unroll
            for (int dw = -1; dw <= 1; ++dw) {
                int hh = h + dh, ww = w + dw;
                bool ok = (hh >= 0) & (hh < H_) & (ww >= 0) & (ww < W_);
                v[(dh + 1) * 3 + dw + 1] = ok ? xp[hh * W_ + ww] : 0.f;
            }
        const float* wc = w_off + c * KK_;
#pragma unroll
        for (int oc = 0; oc < 18; ++oc) {
            const float* wr = wc + oc * CK_;
#pragma unroll
            for (int k = 0; k < KK_; ++k)
                acc[oc] = fmaf(v[k], wr[k], acc[oc]);
        }
    }
#pragma unroll
    for (int oc = 0; oc < 18; ++oc) partial[cg][p][oc] = acc[oc];
    __syncthreads();

    float* po = part + (size_t)sl * (B_ * 18 * HW_);
    for (int e = t; e < 64 * 18; e += 512) {
        int oc = e >> 6;
        int pp = e & 63;
        float s = 0.f;
#pragma unroll
        for (int g = 0; g < 8; ++g) s += partial[g][pp][oc];
        po[((size_t)b * 18 + oc) * HW_ + pos0 + pp] = s;
    }
}

// ---------------------------------------------------------------------------
// Kernel 3b: sum 4 slices + bias -> off.
// ---------------------------------------------------------------------------
__global__ __launch_bounds__(256) void k_offc2(const float* __restrict__ part,
                                               const float* __restrict__ b_off,
                                               float* __restrict__ off) {
    int i = blockIdx.x * 256 + threadIdx.x;   // exact 451584
    const int NP = B_ * 18 * HW_;
    int oc = (i / HW_) % 18;
    off[i] = part[i] + part[i + NP] + part[i + 2 * NP] + part[i + 3 * NP]
           + b_off[oc];
}

// ---------------------------------------------------------------------------
// Kernel 4: FUSED deformable gather + bf16 MFMA GEMM. Tile 128(O) x 64(n),
// K = 2304 (72 kc of 32). No V roundtrip: per kc, corner loads (NHWC
// dwordx4, proven in R5/R6 k_gather) for kc+1 are issued before the MFMA
// phase, bilinear-combined and ds_written to the OTHER B buffer after; A is
// async16-staged to the other A buffer. Single barrier per kc; the barrier's
// vmcnt(0)/lgkmcnt(0) drain lands a full compute phase after load issue.
// O-half pairs share an XCD -> xT corner bytes L2/L1-hit on the 2nd half.
// LDS 43 KB -> 3 blocks/CU; gather VALU co-schedules with MFMA (m114).
// ---------------------------------------------------------------------------
__global__ __launch_bounds__(256) void k_fused(const unsigned short* __restrict__ xT,
                                               const float* __restrict__ off,
                                               const __bf16* __restrict__ wA,
                                               const float* __restrict__ b_dcn,
                                               float* __restrict__ out) {
    __shared__ int    s_id[KK_][64][4];   //  9216 B
    __shared__ float  s_w[KK_][64][4];    //  9216 B
    __shared__ __bf16 s_a[2][128 * 32];   // 16384 B
    __shared__ __bf16 s_b[2][64 * 32];    //  8192 B

    int xk = blockIdx.x;                  // 784
    int u  = (xk >> 4) * 8 + (xk & 7);    // unit 0..391, pairs on same XCD
    int mh = (xk >> 3) & 1;
    int b    = u / 49;
    int pos0 = (u % 49) * 64;
    int ob   = mh * 128;

    int t    = threadIdx.x;
    int lane = t & 63;
    int wv   = t >> 6;
    int lid  = lane & 15;
    int quad = lane >> 4;
    int swz  = swz4(lid);

    // --- bilinear tables (byte offsets into NHWC plane + 4 weights) ---
    for (int e = t; e < KK_ * 64; e += 256) {
        int k = e >> 6, n = e & 63;
        int pos = pos0 + n;
        int h = pos / W_, w = pos % W_;
        float dy = off[((size_t)b * 18 + 2 * k) * HW_ + pos];
        float dx = off[((size_t)b * 18 + 2 * k + 1) * HW_ + pos];
        float py = (float)(h + k / 3 - 1) + dy;
        float px = (float)(w + k % 3 - 1) + dx;
        float y0f = floorf(py), x0f = floorf(px);
        float fy = py - y0f, fx = px - x0f;
        int y0 = (int)y0f, x0 = (int)x0f;
        int y1 = y0 + 1,   x1 = x0 + 1;
        float oy0 = (y0 >= 0 && y0 < H_) ? 1.f : 0.f;
        float oy1 = (y1 >= 0 && y1 < H_) ? 1.f : 0.f;
        float ox0 = (x0 >= 0 && x0 < W_) ? 1.f : 0.f;
        float ox1 = (x1 >= 0 && x1 < W_) ? 1.f : 0.f;
        int y0c = min(max(y0, 0), H_ - 1), y1c = min(max(y1, 0), H_ - 1);
        int x0c = min(max(x0, 0), W_ - 1), x1c = min(max(x1, 0), W_ - 1);
        s_id[k][n][0] = (y0c * W_ + x0c) * 512;   // 256 ch * 2 B
        s_id[k][n][1] = (y0c * W_ + x1c) * 512;
        s_id[k][n][2] = (y1c * W_ + x0c) * 512;
        s_id[k][n][3] = (y1c * W_ + x1c) * 512;
        s_w[k][n][0] = (1.f - fy) * (1.f - fx) * oy0 * ox0;
        s_w[k][n][1] = (1.f - fy) * fx         * oy0 * ox1;
        s_w[k][n][2] = fy * (1.f - fx)         * oy1 * ox0;
        s_w[k][n][3] = fy * fx                 * oy1 * ox1;
    }

    int n   = t >> 2;                     // B-build role: one n, 8 channels
    int tc  = t & 3;
    int scw = tc ^ swz4(n);               // swizzled store chunk
    const char* xb = (const char*)(xT + (size_t)b * HW_ * 256);
    const char* gA0 = (const char*)wA + (size_t)ob * 64;
    int lo = lane * 16;

    f32x4 acc[2][4];
#pragma unroll
    for (int mi = 0; mi < 2; ++mi)
#pragma unroll
        for (int ni = 0; ni < 4; ++ni)
            acc[mi][ni] = (f32x4)(0.f);

    __syncthreads();                      // tables visible

    // --- prologue: stage kc=0 (A via async16, B via regs->bilinear->LDS) ---
    {
        async16(gA0 + wv * 2048 + lo,        (char*)s_a[0] + wv * 2048);
        async16(gA0 + wv * 2048 + 1024 + lo, (char*)s_a[0] + wv * 2048 + 1024);
        int4   id = *(const int4*)s_id[0][n];
        float4 wg = *(const float4*)s_w[0][n];
        const char* p = xb + tc * 16;     // kc=0: tap 0, cs 0
        uint4 c00 = *(const uint4*)(p + id.x);
        uint4 c01 = *(const uint4*)(p + id.y);
        uint4 c10 = *(const uint4*)(p + id.z);
        uint4 c11 = *(const uint4*)(p + id.w);
        uint4 o;
        o.x = pkbf(wg.x*blo(c00.x)+wg.y*blo(c01.x)+wg.z*blo(c10.x)+wg.w*blo(c11.x),
                   wg.x*bhi(c00.x)+wg.y*bhi(c01.x)+wg.z*bhi(c10.x)+wg.w*bhi(c11.x));
        o.y = pkbf(wg.x*blo(c00.y)+wg.y*blo(c01.y)+wg.z*blo(c10.y)+wg.w*blo(c11.y),
                   wg.x*bhi(c00.y)+wg.y*bhi(c01.y)+wg.z*bhi(c10.y)+wg.w*bhi(c11.y));
        o.z = pkbf(wg.x*blo(c00.z)+wg.y*blo(c01.z)+wg.z*blo(c10.z)+wg.w*blo(c11.z),
                   wg.x*bhi(c00.z)+wg.y*bhi(c01.z)+wg.z*bhi(c10.z)+wg.w*bhi(c11.z));
        o.w = pkbf(wg.x*blo(c00.w)+wg.y*blo(c01.w)+wg.z*blo(c10.w)+wg.w*blo(c11.w),
                   wg.x*bhi(c00.w)+wg.y*bhi(c01.w)+wg.z*bhi(c10.w)+wg.w*bhi(c11.w));
        *(uint4*)((char*)s_b[0] + n * 64 + scw * 16) = o;
    }
    __syncthreads();

    for (int kc = 0; kc < NKC; ++kc) {
        int cur = kc & 1, nxt = cur ^ 1;
        // 1. fragment reads from current buffers
        const bf16x8* pa = (const bf16x8*)s_a[cur];
        const bf16x8* pb = (const bf16x8*)s_b[cur];
        bf16x8 af[2], bfv[4];
#pragma unroll
        for (int mi = 0; mi < 2; ++mi)
            af[mi] = pa[(wv * 32 + mi * 16 + lid) * 4 + (quad ^ swz)];
#pragma unroll
        for (int ni = 0; ni < 4; ++ni)
            bfv[ni] = pb[(ni * 16 + lid) * 4 + (quad ^ swz)];

        // 2. issue prefetch for kc+1 (corner regs + async16 A -> nxt)
        uint4 c00, c01, c10, c11;
        float4 wg;
        bool valid = (kc + 1) < NKC;
        if (valid) {
            int kn  = kc + 1;
            int tap = kn >> 3, cs = kn & 7;
            int4 id = *(const int4*)s_id[tap][n];
            wg = *(const float4*)s_w[tap][n];
            const char* p = xb + (cs * 32 + tc * 8) * 2;
            c00 = *(const uint4*)(p + id.x);
            c01 = *(const uint4*)(p + id.y);
            c10 = *(const uint4*)(p + id.z);
            c11 = *(const uint4*)(p + id.w);
            const char* ga = gA0 + (size_t)kn * 16384;
            async16(ga + wv * 2048 + lo,        (char*)s_a[nxt] + wv * 2048);
            async16(ga + wv * 2048 + 1024 + lo, (char*)s_a[nxt] + wv * 2048 + 1024);
        }

        // 3. MFMA on current fragments
#pragma unroll
        for (int mi = 0; mi < 2; ++mi)
#pragma unroll
            for (int ni = 0; ni < 4; ++ni)
                acc[mi][ni] = __builtin_amdgcn_mfma_f32_16x16x32_bf16(
                    af[mi], bfv[ni], acc[mi][ni], 0, 0, 0);

        // 4. bilinear combine + store B(kc+1) to nxt buffer
        if (valid) {
            uint4 o;
            o.x = pkbf(wg.x*blo(c00.x)+wg.y*blo(c01.x)+wg.z*blo(c10.x)+wg.w*blo(c11.x),
                       wg.x*bhi(c00.x)+wg.y*bhi(c01.x)+wg.z*bhi(c10.x)+wg.w*bhi(c11.x));
            o.y = pkbf(wg.x*blo(c00.y)+wg.y*blo(c01.y)+wg.z*blo(c10.y)+wg.w*blo(c11.y),
                       wg.x*bhi(c00.y)+wg.y*bhi(c01.y)+wg.z*bhi(c10.y)+wg.w*bhi(c11.y));
            o.z = pkbf(wg.x*blo(c00.z)+wg.y*blo(c01.z)+wg.z*blo(c10.z)+wg.w*blo(c11.z),
                       wg.x*bhi(c00.z)+wg.y*bhi(c01.z)+wg.z*bhi(c10.z)+wg.w*bhi(c11.z));
            o.w = pkbf(wg.x*blo(c00.w)+wg.y*blo(c01.w)+wg.z*blo(c10.w)+wg.w*blo(c11.w),
                       wg.x*bhi(c00.w)+wg.y*bhi(c01.w)+wg.z*bhi(c10.w)+wg.w*bhi(c11.w));
            *(uint4*)((char*)s_b[nxt] + n * 64 + scw * 16) = o;
        }
        __syncthreads();
    }

    // epilogue: bias + store. D: col(n)=lane&15, row(m)=quad*4+reg
#pragma unroll
    for (int mi = 0; mi < 2; ++mi) {
#pragma unroll
        for (int r = 0; r < 4; ++r) {
            int m = wv * 32 + mi * 16 + quad * 4 + r;
            int o = ob + m;
            float bias = b_dcn[o];
            float* po = out + ((size_t)b * O_ + o) * HW_ + pos0 + lid;
#pragma unroll
            for (int ni = 0; ni < 4; ++ni)
                po[ni * 16] = acc[mi][ni][r] + bias;
        }
    }
}

extern "C" void kernel_launch(void* const* d_in, const int* in_sizes, int n_in,
                              void* d_out, int out_size, void* d_ws, size_t ws_size,
                              hipStream_t stream) {
    const float* x     = (const float*)d_in[0];
    const float* w_off = (const float*)d_in[1];
    const float* b_off = (const float*)d_in[2];
    const float* w_dcn = (const float*)d_in[3];
    const float* b_dcn = (const float*)d_in[4];
    float* out = (float*)d_out;

    // ws: off 1.81 | wA 1.18 | xT 12.85 | part 7.23  (23.1 MB total)
    const size_t offBytes  = (size_t)451584 * 4;
    const size_t wABytes   = (size_t)589824 * 2;
    const size_t xTBytes   = (size_t)B_ * HW_ * 256 * 2;
    float*          off  = (float*)d_ws;
    unsigned short* wA   = (unsigned short*)((char*)d_ws + offBytes);
    unsigned short* xT   = (unsigned short*)((char*)d_ws + offBytes + wABytes);
    float*          part = (float*)((char*)d_ws + offBytes + wABytes + xTBytes);

    k_buildA <<<2304, 256, 0, stream>>>(w_dcn, wA);
    k_transx <<<1568, 256, 0, stream>>>(x, xT);
    k_offc1  <<<1568, 512, 0, stream>>>(x, w_off, part);
    k_offc2  <<<1764, 256, 0, stream>>>(part, b_off, off);
    k_fused  <<<784, 256, 0, stream>>>(xT, off, (const __bf16*)wA, b_dcn, out);
}